// Round 10
// baseline (240.767 us; speedup 1.0000x reference)
//
#include <hip/hip_runtime.h>
#include <hip/hip_bf16.h>
#include <math.h>

#define BB 2
#define CC 1024
#define TT 2048
#define HH 16
#define DD 64

using short8   = __attribute__((ext_vector_type(8))) short;
using floatx4  = __attribute__((ext_vector_type(4))) float;
using floatx16 = __attribute__((ext_vector_type(16))) float;
typedef unsigned short ushort_t;

#define MFMA(a, b, c) __builtin_amdgcn_mfma_f32_16x16x32_bf16((a), (b), (c), 0, 0, 0)
#define MFMA32(a, b, c) __builtin_amdgcn_mfma_f32_32x32x16_bf16((a), (b), (c), 0, 0, 0)

// Q pre-scale: SCALE * log2(e) so attn softmax runs in exp2 domain.
#define QSC 0.18033688011112042f

// Schraudolph fast exp2: 2 full-rate VALU ops (fma + cvt) vs 8-cyc v_exp_f32.
// B chosen fp32-representable so approx(0) is a bit-exact compile-time const.
#define SCHRAU_B 1064866816.0f
#define SCHRAU_I0 1064866816          // (int)SCHRAU_B ; approx(0) = bits(I0)
__device__ __forceinline__ float exp2_approx(float x) {
    int i = (int)(fmaf(x, 8388608.0f, SCHRAU_B));
    return __int_as_float(i);
}

__device__ __forceinline__ ushort_t f2bf(float f) {
    unsigned int u = __float_as_uint(f);
    u += 0x7FFFu + ((u >> 16) & 1u);
    return (ushort_t)(u >> 16);
}
__device__ __forceinline__ float bf2f(ushort_t h) {
    return __uint_as_float(((unsigned int)h) << 16);
}
// single v_perm_b32: pack high halves of two floats (truncation to bf16)
__device__ __forceinline__ unsigned int packtrunc(float a, float b) {
    return __builtin_amdgcn_perm(__float_as_uint(b), __float_as_uint(a),
                                 0x07060302u);
}
// async global->LDS, 16B per lane, dest = uniform base + lane*16
__device__ __forceinline__ void load_lds16(const void* g, void* s) {
    __builtin_amdgcn_global_load_lds(
        (const __attribute__((address_space(1))) void*)g,
        (__attribute__((address_space(3))) void*)s, 16, 0, 0);
}

// ---- workspace byte offsets (bf16 arena starts at 64KB) --------------------
static constexpr size_t B0       = 65536;
static constexpr size_t XT_OFF   = B0;                       // [B][T][C] bf16; later reused for OT
static constexpr size_t WQKV_OFF = XT_OFF   + 8388608;       // [3072][1024]
static constexpr size_t WP_OFF   = WQKV_OFF + 6291456;       // [1024][1024]
static constexpr size_t Q_OFF    = WP_OFF   + 2097152;       // [B][H][T][D]
static constexpr size_t K_OFF    = Q_OFF    + 8388608;
static constexpr size_t V_OFF    = K_OFF    + 8388608;       // [B][C][T]
static constexpr size_t OP_OFF   = V_OFF    + 8388608;       // Opart[2][B][T][C] bf16
static constexpr size_t ML_OFF   = OP_OFF   + 16777216;      // l[2][B][H][T] fp32

// ---------------------------------------------------------------------------
// Mask detect; also zeroes the per-(b,split) masked-key counters nm[4].
// ---------------------------------------------------------------------------
__global__ void detect_mask_kernel(const unsigned int* __restrict__ raw,
                                   int* __restrict__ flags) {
    __shared__ int ev_bf16, ev_bool;
    if (threadIdx.x == 0) { ev_bf16 = 0; ev_bool = 0; }
    __syncthreads();
    for (int i = threadIdx.x; i < 1024; i += 256) {
        unsigned int w = raw[i];
        if ((w & 0xFFFFu) == 0x3F80u) atomicOr(&ev_bf16, 1);
        if ((w & 0xFFFFFF00u) != 0u && w != 0x3F800000u) atomicOr(&ev_bool, 1);
    }
    __syncthreads();
    if (threadIdx.x == 0) flags[0] = ev_bf16 ? 2 : (ev_bool ? 1 : 0);
    if (threadIdx.x < 4) flags[8 + threadIdx.x] = 0;   // nm[b][sp] counters
}

// maskf = {0,1}; count masked keys per (b, split); echo mask to out tail.
__global__ void expand_mask_kernel(const void* __restrict__ raw,
                                   const int* __restrict__ flags,
                                   float* __restrict__ maskf,
                                   int* __restrict__ nmask,
                                   float* __restrict__ out_tail) {
    int e = blockIdx.x * 256 + threadIdx.x;
    if (e >= BB * TT) return;
    int mode = flags[0];
    bool on;
    if (mode == 2)      on = ((const ushort_t*)raw)[e] != 0;
    else if (mode == 1) on = ((const unsigned char*)raw)[e] != 0;
    else                on = ((const unsigned int*)raw)[e] != 0;
    maskf[e]    = on ? 1.0f : 0.0f;
    out_tail[e] = on ? 1.0f : 0.0f;
    if (!on) {
        int b = e >> 11, sp = (e >> 10) & 1;
        atomicAdd(&nmask[b * 2 + sp], 1);
    }
}

// ---------------------------------------------------------------------------
// x [B][C][T] fp32 -> XT [B][T][C] bf16 (64x64 tiles via LDS)
// ---------------------------------------------------------------------------
__global__ __launch_bounds__(256) void xpose_kernel(const float* __restrict__ x,
                                                    ushort_t* __restrict__ XT) {
    __shared__ float tile[64][65];
    const int t0 = blockIdx.x * 64, c0 = blockIdx.y * 64, b = blockIdx.z;
    const int tid = threadIdx.x;
    const int tc = tid & 15, tr = tid >> 4;
    #pragma unroll
    for (int p = 0; p < 4; p++) {
        int cl = tr + p * 16;
        float4 v = *(const float4*)&x[((size_t)b * CC + c0 + cl) * TT + t0 + tc * 4];
        tile[cl][tc * 4 + 0] = v.x; tile[cl][tc * 4 + 1] = v.y;
        tile[cl][tc * 4 + 2] = v.z; tile[cl][tc * 4 + 3] = v.w;
    }
    __syncthreads();
    #pragma unroll
    for (int p = 0; p < 4; p++) {
        int tl = tr + p * 16;
        ushort4 pk;
        pk.x = f2bf(tile[tc * 4 + 0][tl]);
        pk.y = f2bf(tile[tc * 4 + 1][tl]);
        pk.z = f2bf(tile[tc * 4 + 2][tl]);
        pk.w = f2bf(tile[tc * 4 + 3][tl]);
        *(ushort4*)&XT[((size_t)b * TT + t0 + tl) * CC + c0 + tc * 4] = pk;
    }
}

// ---------------------------------------------------------------------------
// Weights -> bf16: WQKV [3072][1024], WP [1024][1024].
// ---------------------------------------------------------------------------
__global__ __launch_bounds__(256) void convert_w_kernel(
    const float* __restrict__ Wq, const float* __restrict__ Wk,
    const float* __restrict__ Wv, const float* __restrict__ Wp,
    ushort_t* __restrict__ WQKV, ushort_t* __restrict__ WP) {
    const int idx = blockIdx.x * 256 + threadIdx.x;  // quad index
    if (idx < 786432) {
        int row = idx >> 8;
        int qc  = idx & 255;
        const float* src = row < 1024 ? Wq : (row < 2048 ? Wk : Wv);
        float4 v = *(const float4*)&src[(size_t)(row & 1023) * CC + qc * 4];
        ushort4 pk; pk.x = f2bf(v.x); pk.y = f2bf(v.y); pk.z = f2bf(v.z); pk.w = f2bf(v.w);
        *(ushort4*)&WQKV[(size_t)idx * 4] = pk;
    } else {
        int j = idx - 786432;
        float4 v = *(const float4*)&Wp[(size_t)j * 4];
        ushort4 pk; pk.x = f2bf(v.x); pk.y = f2bf(v.y); pk.z = f2bf(v.z); pk.w = f2bf(v.w);
        *(ushort4*)&WP[(size_t)j * 4] = pk;
    }
}

// ---------------------------------------------------------------------------
// Fused QKV GEMM. q pre-scaled by QSC; K,V MASKED COLUMNS ZEROED.
// maskf loads hoisted before the K-loop (off the epilogue dependency chain).
// ---------------------------------------------------------------------------
__global__ __launch_bounds__(256) void gemm_qkv_kernel(
    const ushort_t* __restrict__ Wqkv, const float* __restrict__ bq,
    const float* __restrict__ bk, const float* __restrict__ bv,
    const ushort_t* __restrict__ XT, const float* __restrict__ maskf,
    ushort_t* __restrict__ Qo, ushort_t* __restrict__ Ko,
    ushort_t* __restrict__ Vo) {
    __shared__ ushort_t As[128][32];
    __shared__ ushort_t Bs[128][32];
    __shared__ float biasS[128];

    const int b = blockIdx.z;
    const int m0 = blockIdx.y * 128;
    const int n0 = blockIdx.x * 128;
    const int tid = threadIdx.x;
    const int lane = tid & 63;
    const int w = tid >> 6;
    const int wm = (w & 1) * 64, wn = (w >> 1) * 64;
    const int la = lane & 15, lg = lane >> 4;
    const int region = m0 >> 10;  // 0=q 1=k 2=v

    const float* bsrc = region == 0 ? (bq + m0)
                      : (region == 1 ? (bk + m0 - 1024) : (bv + m0 - 2048));
    if (tid < 128) biasS[tid] = bsrc[tid];

    // per-column scale, loaded up-front: Q -> QSC; K,V -> mask
    float csc[4];
    #pragma unroll
    for (int nt = 0; nt < 4; nt++) {
        const int t = n0 + wn + nt * 16 + la;
        csc[nt] = (region == 0) ? QSC : maskf[b * TT + t];
    }

    floatx4 zero4 = {0.f, 0.f, 0.f, 0.f};
    floatx4 acc[4][4];
    #pragma unroll
    for (int mt = 0; mt < 4; mt++)
        #pragma unroll
        for (int nt = 0; nt < 4; nt++) acc[mt][nt] = zero4;

    const ushort_t* Abase = Wqkv + (size_t)m0 * CC;
    const ushort_t* Bbase = XT + ((size_t)b * TT + n0) * CC;
    const int rl = lane >> 2;
    const int cl = (lane & 3) * 8;

    for (int k0 = 0; k0 < CC; k0 += 32) {
        #pragma unroll
        for (int c = 0; c < 2; c++) {
            int row = w * 32 + c * 16;
            load_lds16(Abase + (size_t)(row + rl) * CC + k0 + cl, &As[row][0]);
            load_lds16(Bbase + (size_t)(row + rl) * CC + k0 + cl, &Bs[row][0]);
        }
        __syncthreads();
        short8 af[4], bf[4];
        #pragma unroll
        for (int mt = 0; mt < 4; mt++)
            af[mt] = *(const short8*)&As[wm + mt * 16 + la][lg * 8];
        #pragma unroll
        for (int nt = 0; nt < 4; nt++)
            bf[nt] = *(const short8*)&Bs[wn + nt * 16 + la][lg * 8];
        #pragma unroll
        for (int mt = 0; mt < 4; mt++)
            #pragma unroll
            for (int nt = 0; nt < 4; nt++)
                acc[mt][nt] = MFMA(af[mt], bf[nt], acc[mt][nt]);
        __syncthreads();
    }

    #pragma unroll
    for (int mt = 0; mt < 4; mt++) {
        const int lm = wm + mt * 16 + lg * 4;
        const int gm = m0 + lm;
        #pragma unroll
        for (int nt = 0; nt < 4; nt++) {
            const int t = n0 + wn + nt * 16 + la;
            const float sc = csc[nt];
            float v0 = (acc[mt][nt][0] + biasS[lm + 0]) * sc;
            float v1 = (acc[mt][nt][1] + biasS[lm + 1]) * sc;
            float v2 = (acc[mt][nt][2] + biasS[lm + 2]) * sc;
            float v3 = (acc[mt][nt][3] + biasS[lm + 3]) * sc;
            if (region < 2) {
                int mq = gm & 1023;
                int hh = mq >> 6, db = mq & 63;
                ushort_t* dst = (region == 0 ? Qo : Ko)
                              + (((size_t)b * HH + hh) * TT + t) * DD + db;
                ushort4 pk; pk.x = f2bf(v0); pk.y = f2bf(v1);
                pk.z = f2bf(v2); pk.w = f2bf(v3);
                *(ushort4*)dst = pk;
            } else {
                int c = gm & 1023;
                Vo[((size_t)b * CC + c + 0) * TT + t] = f2bf(v0);
                Vo[((size_t)b * CC + c + 1) * TT + t] = f2bf(v1);
                Vo[((size_t)b * CC + c + 2) * TT + t] = f2bf(v2);
                Vo[((size_t)b * CC + c + 3) * TT + t] = f2bf(v3);
            }
        }
    }
}

// ---------------------------------------------------------------------------
// Flash attention v7: split-K=2, 32x32x16 MFMA, Q in regs, bias-free inner
// loop, SCHRAUDOLPH exp2 (2 full-rate VALU vs 8-cyc transcendental).
// Masked keys: K/V cols zero -> s=0 -> p=approx(0)=bits(SCHRAU_I0) exactly;
// l corrected by nmask * that constant.
// ---------------------------------------------------------------------------
__global__ __launch_bounds__(256) void attn_kernel(
    const ushort_t* __restrict__ Qg, const ushort_t* __restrict__ Kg,
    const ushort_t* __restrict__ Vg, const int* __restrict__ nmask,
    ushort_t* __restrict__ Opart, float* __restrict__ lbuf) {
    __shared__ ushort_t Ks[2][64][72];   // [buf][key][d]
    __shared__ ushort_t Vs[2][64][72];   // [buf][d][key]

    const int sp = blockIdx.z & 1, b = blockIdx.z >> 1;
    const int hh = blockIdx.y, t0 = blockIdx.x * 128;
    const int j0base = sp * (TT / 2);
    const int tid  = threadIdx.x;
    const int lane = tid & 63;
    const int w    = tid >> 6;
    const int ln31 = lane & 31;
    const int h    = lane >> 5;
    const size_t qkbase = ((size_t)b * HH + hh) * TT * DD;
    const size_t vbase  = ((size_t)b * CC + hh * DD) * TT;

    const int tq = t0 + w * 32 + ln31;
    short8 qreg[4];
    {
        const ushort_t* qp = Qg + qkbase + (size_t)tq * DD + h * 8;
        #pragma unroll
        for (int kc = 0; kc < 4; kc++)
            qreg[kc] = *(const short8*)(qp + kc * 16);
    }

    const int srow = tid >> 2;
    const int scol = (tid & 3) * 16;

    int4 kpre0, kpre1, vpre0, vpre1;
    {
        const ushort_t* kp = Kg + qkbase + (size_t)(j0base + srow) * DD + scol;
        const ushort_t* vp = Vg + vbase + (size_t)srow * TT + j0base + scol;
        kpre0 = *(const int4*)(kp);  kpre1 = *(const int4*)(kp + 8);
        vpre0 = *(const int4*)(vp);  vpre1 = *(const int4*)(vp + 8);
    }

    float lsum = 0.0f;
    floatx16 zero16 = {0.f,0.f,0.f,0.f,0.f,0.f,0.f,0.f,
                       0.f,0.f,0.f,0.f,0.f,0.f,0.f,0.f};
    floatx16 oacc[2];
    oacc[0] = zero16; oacc[1] = zero16;

    for (int kt = 0; kt < 16; kt++) {
        const int p = kt & 1;
        *(int4*)&Ks[p][srow][scol]     = kpre0;
        *(int4*)&Ks[p][srow][scol + 8] = kpre1;
        *(int4*)&Vs[p][srow][scol]     = vpre0;
        *(int4*)&Vs[p][srow][scol + 8] = vpre1;
        if (kt < 15) {
            const int j0n = j0base + (kt + 1) * 64;
            const ushort_t* kp = Kg + qkbase + (size_t)(j0n + srow) * DD + scol;
            const ushort_t* vp = Vg + vbase + (size_t)srow * TT + j0n + scol;
            kpre0 = *(const int4*)(kp);  kpre1 = *(const int4*)(kp + 8);
            vpre0 = *(const int4*)(vp);  vpre1 = *(const int4*)(vp + 8);
        }
        __syncthreads();

        // ---- S^T = K · Q^T ----
        floatx16 sacc[2];
        sacc[0] = zero16; sacc[1] = zero16;
        #pragma unroll
        for (int kc = 0; kc < 4; kc++) {
            #pragma unroll
            for (int mt = 0; mt < 2; mt++) {
                short8 kf = *(const short8*)&Ks[p][mt * 32 + ln31][kc * 16 + h * 8];
                sacc[mt] = MFMA32(kf, qreg[kc], sacc[mt]);
            }
        }

        // ---- Schraudolph exp2 softmax: p = approx2^s ----
        float psum = 0.0f;
        unsigned int pd[16];
        #pragma unroll
        for (int mt = 0; mt < 2; mt++)
            #pragma unroll
            for (int g = 0; g < 4; g++) {
                float p0 = exp2_approx(sacc[mt][g * 4 + 0]);
                float p1 = exp2_approx(sacc[mt][g * 4 + 1]);
                float p2 = exp2_approx(sacc[mt][g * 4 + 2]);
                float p3 = exp2_approx(sacc[mt][g * 4 + 3]);
                psum += (p0 + p1) + (p2 + p3);
                pd[mt * 8 + g * 2 + 0] = packtrunc(p0, p1);
                pd[mt * 8 + g * 2 + 1] = packtrunc(p2, p3);
            }
        lsum += psum;

        // ---- PV: B-frag via half-wave exchange ----
        #pragma unroll
        for (int kc = 0; kc < 4; kc++) {
            const int base = (kc >> 1) * 8 + (kc & 1) * 4;
            int a0 = pd[base], a1 = pd[base + 1], a2 = pd[base + 2], a3 = pd[base + 3];
            int x0 = __shfl_xor(h ? a0 : a2, 32, 64);
            int x1 = __shfl_xor(h ? a1 : a3, 32, 64);
            int4 fi;
            fi.x = h ? x0 : a0;
            fi.y = h ? x1 : a1;
            fi.z = h ? a2 : x0;
            fi.w = h ? a3 : x1;
            short8 pf = *(short8*)&fi;
            #pragma unroll
            for (int dt = 0; dt < 2; dt++) {
                short8 vf = *(const short8*)&Vs[p][dt * 32 + ln31][kc * 16 + h * 8];
                oacc[dt] = MFMA32(vf, pf, oacc[dt]);
            }
        }
    }

    // full split sum; remove masked keys' exact approx(0) contributions
    lsum += __shfl_xor(lsum, 32, 64);
    lsum -= (float)nmask[b * 2 + sp] * __int_as_float(SCHRAU_I0);

    // ---- epilogue: Opart = O_s/l_s (bf16), l_s to lbuf ----
    const float inv = lsum > 0.0f ? 1.0f / lsum : 0.0f;
    ushort_t* OP = Opart + (size_t)sp * ((size_t)BB * TT * CC)
                 + ((size_t)b * TT + tq) * CC + hh * 64;
    #pragma unroll
    for (int mt = 0; mt < 2; mt++)
        #pragma unroll
        for (int g = 0; g < 4; g++) {
            int db = mt * 32 + g * 8 + h * 4;
            ushort4 pk;
            pk.x = f2bf(oacc[mt][g * 4 + 0] * inv);
            pk.y = f2bf(oacc[mt][g * 4 + 1] * inv);
            pk.z = f2bf(oacc[mt][g * 4 + 2] * inv);
            pk.w = f2bf(oacc[mt][g * 4 + 3] * inv);
            *(ushort4*)&OP[db] = pk;
        }
    if (h == 0)
        lbuf[(((size_t)sp * BB + b) * HH + hh) * TT + tq] = lsum;
}

// ---------------------------------------------------------------------------
// Combine splits: OT = w0*P0 + w1*P1, w_s = l_s/(l0+l1).
// ---------------------------------------------------------------------------
__global__ __launch_bounds__(256) void combine_kernel(
    const ushort_t* __restrict__ Opart, const float* __restrict__ lbuf,
    ushort_t* __restrict__ OT) {
    const size_t idx = ((size_t)blockIdx.x * 256 + threadIdx.x) * 8;
    const int c0 = (int)(idx & (CC - 1));
    const int t  = (int)((idx >> 10) & (TT - 1));
    const int b  = (int)(idx >> 21);
    const int hh = c0 >> 6;
    const float l0 = lbuf[(((size_t)0 * BB + b) * HH + hh) * TT + t];
    const float l1 = lbuf[(((size_t)1 * BB + b) * HH + hh) * TT + t];
    const float sum = l0 + l1;
    const float ws = sum > 0.0f ? 1.0f / sum : 0.0f;
    const float w0 = l0 * ws, w1 = l1 * ws;
    const ushort_t* P0 = Opart + idx;
    const ushort_t* P1 = Opart + (size_t)BB * TT * CC + idx;
    ushort4 a0 = *(const ushort4*)(P0);
    ushort4 a1 = *(const ushort4*)(P0 + 4);
    ushort4 b0 = *(const ushort4*)(P1);
    ushort4 b1 = *(const ushort4*)(P1 + 4);
    ushort4 o0, o1;
    o0.x = f2bf(w0 * bf2f(a0.x) + w1 * bf2f(b0.x));
    o0.y = f2bf(w0 * bf2f(a0.y) + w1 * bf2f(b0.y));
    o0.z = f2bf(w0 * bf2f(a0.z) + w1 * bf2f(b0.z));
    o0.w = f2bf(w0 * bf2f(a0.w) + w1 * bf2f(b0.w));
    o1.x = f2bf(w0 * bf2f(a1.x) + w1 * bf2f(b1.x));
    o1.y = f2bf(w0 * bf2f(a1.y) + w1 * bf2f(b1.y));
    o1.z = f2bf(w0 * bf2f(a1.z) + w1 * bf2f(b1.z));
    o1.w = f2bf(w0 * bf2f(a1.w) + w1 * bf2f(b1.w));
    *(ushort4*)&OT[idx]     = o0;
    *(ushort4*)&OT[idx + 4] = o1;
}

// ---------------------------------------------------------------------------
// Output GEMM, single-pass bf16 (proven R7/R8).
// ---------------------------------------------------------------------------
__global__ __launch_bounds__(256) void gemm_out_kernel(
    const ushort_t* __restrict__ WP, const ushort_t* __restrict__ OT,
    const float* __restrict__ bp, const float* __restrict__ maskf,
    float* __restrict__ out) {
    __shared__ ushort_t As[64][32];
    __shared__ ushort_t Bs[128][32];
    __shared__ float biasS[64];

    const int b = blockIdx.z;
    const int m0 = blockIdx.y * 64;
    const int n0 = blockIdx.x * 128;
    const int tid = threadIdx.x;
    const int lane = tid & 63;
    const int w = tid >> 6;
    const int wm = (w & 1) * 32, wn = (w >> 1) * 64;
    const int la = lane & 15, lg = lane >> 4;

    if (tid < 64) biasS[tid] = bp[m0 + tid];

    floatx4 zero4 = {0.f, 0.f, 0.f, 0.f};
    floatx4 acc[2][4];
    #pragma unroll
    for (int mt = 0; mt < 2; mt++)
        #pragma unroll
        for (int nt = 0; nt < 4; nt++) acc[mt][nt] = zero4;

    const int rl = lane >> 2;
    const int cl = (lane & 3) * 8;
    const ushort_t* Bbase = OT + ((size_t)b * TT + n0) * CC;

    for (int k0 = 0; k0 < CC; k0 += 32) {
        {
            int row = w * 16;
            load_lds16(WP + (size_t)(m0 + row + rl) * CC + k0 + cl, &As[row][0]);
        }
        #pragma unroll
        for (int c = 0; c < 2; c++) {
            int row = w * 32 + c * 16;
            load_lds16(Bbase + (size_t)(row + rl) * CC + k0 + cl, &Bs[row][0]);
        }
        __syncthreads();
        short8 af[2], bf[4];
        #pragma unroll
        for (int mt = 0; mt < 2; mt++)
            af[mt] = *(const short8*)&As[wm + mt * 16 + la][lg * 8];
        #pragma unroll
        for (int nt = 0; nt < 4; nt++)
            bf[nt] = *(const short8*)&Bs[wn + nt * 16 + la][lg * 8];
        #pragma unroll
        for (int mt = 0; mt < 2; mt++)
            #pragma unroll
            for (int nt = 0; nt < 4; nt++)
                acc[mt][nt] = MFMA(af[mt], bf[nt], acc[mt][nt]);
        __syncthreads();
    }

    #pragma unroll
    for (int mt = 0; mt < 2; mt++) {
        const int lm = wm + mt * 16 + lg * 4;
        #pragma unroll
        for (int nt = 0; nt < 4; nt++) {
            const int t = n0 + wn + nt * 16 + la;
            const float mk = maskf[b * TT + t];
            #pragma unroll
            for (int r = 0; r < 4; r++)
                out[((size_t)b * CC + m0 + lm + r) * TT + t] =
                    (acc[mt][nt][r] + biasS[lm + r]) * mk;
        }
    }
}

// ---------------------------------------------------------------------------
extern "C" void kernel_launch(void* const* d_in, const int* in_sizes, int n_in,
                              void* d_out, int out_size, void* d_ws,
                              size_t ws_size, hipStream_t stream) {
    const float* x    = (const float*)d_in[0];
    const void*  mask = d_in[1];
    const float* Wq   = (const float*)d_in[2];
    const float* bq   = (const float*)d_in[3];
    const float* Wk   = (const float*)d_in[4];
    const float* bk   = (const float*)d_in[5];
    const float* Wv   = (const float*)d_in[6];
    const float* bv   = (const float*)d_in[7];
    const float* Wp   = (const float*)d_in[8];
    const float* bp   = (const float*)d_in[9];

    float* out  = (float*)d_out;
    float* wsf  = (float*)d_ws;
    int* flags  = (int*)d_ws;          // [0]=mode, [8..11]=nmask[b][sp]
    int* nmask  = flags + 8;
    float* maskf = wsf + 1024;
    char* wsb = (char*)d_ws;
    ushort_t* XT    = (ushort_t*)(wsb + XT_OFF);   // also final OT
    ushort_t* WQKV  = (ushort_t*)(wsb + WQKV_OFF);
    ushort_t* WPb   = (ushort_t*)(wsb + WP_OFF);
    ushort_t* Qb    = (ushort_t*)(wsb + Q_OFF);
    ushort_t* Kb    = (ushort_t*)(wsb + K_OFF);
    ushort_t* Vb    = (ushort_t*)(wsb + V_OFF);
    ushort_t* Opart = (ushort_t*)(wsb + OP_OFF);
    float*    lbuf  = (float*)(wsb + ML_OFF);

    detect_mask_kernel<<<1, 256, 0, stream>>>((const unsigned int*)mask, flags);
    expand_mask_kernel<<<16, 256, 0, stream>>>(mask, flags, maskf, nmask,
                                               out + (size_t)BB * CC * TT);
    xpose_kernel<<<dim3(TT / 64, CC / 64, BB), 256, 0, stream>>>(x, XT);
    convert_w_kernel<<<4096, 256, 0, stream>>>(Wq, Wk, Wv, Wp, WQKV, WPb);

    gemm_qkv_kernel<<<dim3(TT / 128, 3 * CC / 128, BB), 256, 0, stream>>>(
        WQKV, bq, bk, bv, XT, maskf, Qb, Kb, Vb);

    attn_kernel<<<dim3(TT / 128, HH, BB * 2), 256, 0, stream>>>(
        Qb, Kb, Vb, nmask, Opart, lbuf);

    combine_kernel<<<2048, 256, 0, stream>>>(Opart, lbuf, XT);

    gemm_out_kernel<<<dim3(TT / 128, CC / 64, BB), 256, 0, stream>>>(
        WPb, XT, bp, maskf, out);
}

// Round 11
// 208.095 us; speedup vs baseline: 1.1570x; 1.1570x over previous
//
#include <hip/hip_runtime.h>
#include <hip/hip_bf16.h>
#include <math.h>

#define BB 2
#define CC 1024
#define TT 2048
#define HH 16
#define DD 64

using short8   = __attribute__((ext_vector_type(8))) short;
using floatx4  = __attribute__((ext_vector_type(4))) float;
using floatx16 = __attribute__((ext_vector_type(16))) float;
typedef unsigned short ushort_t;

#define MFMA(a, b, c) __builtin_amdgcn_mfma_f32_16x16x32_bf16((a), (b), (c), 0, 0, 0)
#define MFMA32(a, b, c) __builtin_amdgcn_mfma_f32_32x32x16_bf16((a), (b), (c), 0, 0, 0)

// Q pre-scale: SCALE * log2(e) so attn softmax runs in exp2 domain.
#define QSC 0.18033688011112042f

// Schraudolph fast exp2 (2 full-rate VALU ops). approx(0) = bits(SCHRAU_I0).
#define SCHRAU_B 1064866816.0f
#define SCHRAU_I0 1064866816
__device__ __forceinline__ float exp2_approx(float x) {
    int i = (int)(fmaf(x, 8388608.0f, SCHRAU_B));
    return __int_as_float(i);
}

__device__ __forceinline__ ushort_t f2bf(float f) {          // RNE (O-path)
    unsigned int u = __float_as_uint(f);
    u += 0x7FFFu + ((u >> 16) & 1u);
    return (ushort_t)(u >> 16);
}
__device__ __forceinline__ float bf2f(ushort_t h) {
    return __uint_as_float(((unsigned int)h) << 16);
}
__device__ __forceinline__ ushort_t f2bf_t(float f) {        // truncation
    return (ushort_t)(__float_as_uint(f) >> 16);
}
// single v_perm_b32: pack high halves of two floats (truncation to bf16)
__device__ __forceinline__ unsigned int packtrunc(float a, float b) {
    return __builtin_amdgcn_perm(__float_as_uint(b), __float_as_uint(a),
                                 0x07060302u);
}
// async global->LDS, 16B per lane, dest = uniform base + lane*16
__device__ __forceinline__ void load_lds16(const void* g, void* s) {
    __builtin_amdgcn_global_load_lds(
        (const __attribute__((address_space(1))) void*)g,
        (__attribute__((address_space(3))) void*)s, 16, 0, 0);
}

// ---- workspace byte offsets (bf16 arena starts at 64KB) --------------------
static constexpr size_t B0       = 65536;
static constexpr size_t XT_OFF   = B0;                       // [B][T][C] bf16; later reused for OT
static constexpr size_t WQKV_OFF = XT_OFF   + 8388608;       // [3072][1024]
static constexpr size_t WP_OFF   = WQKV_OFF + 6291456;       // [1024][1024]
static constexpr size_t Q_OFF    = WP_OFF   + 2097152;       // [B][H][T][D]
static constexpr size_t K_OFF    = Q_OFF    + 8388608;
static constexpr size_t V_OFF    = K_OFF    + 8388608;       // [B][C][T]
static constexpr size_t OP_OFF   = V_OFF    + 8388608;       // Opart[2][B][T][C] bf16
static constexpr size_t ML_OFF   = OP_OFF   + 16777216;      // l[2][B][H][T] fp32

// ---------------------------------------------------------------------------
// Merged mask kernel: 16 blocks x 256. Each block self-detects the mask dtype
// (redundant scan of first 1024 words — free), expands its 256 elements, and
// writes its masked-key count to a private slot (no global atomics, no zeroing
// dependency). Region (b,sp) = bid>>2; nmask(b,sp) = sum of its 4 slots.
// ---------------------------------------------------------------------------
__global__ __launch_bounds__(256) void mask_kernel(
    const unsigned int* __restrict__ raw, float* __restrict__ maskf,
    int* __restrict__ nmcnt, float* __restrict__ out_tail) {
    __shared__ int ev_bf16, ev_bool, cnt;
    const int tid = threadIdx.x;
    if (tid == 0) { ev_bf16 = 0; ev_bool = 0; cnt = 0; }
    __syncthreads();
    for (int i = tid; i < 1024; i += 256) {
        unsigned int w = raw[i];
        if ((w & 0xFFFFu) == 0x3F80u) atomicOr(&ev_bf16, 1);
        if ((w & 0xFFFFFF00u) != 0u && w != 0x3F800000u) atomicOr(&ev_bool, 1);
    }
    __syncthreads();
    const int mode = ev_bf16 ? 2 : (ev_bool ? 1 : 0);
    const int e = blockIdx.x * 256 + tid;
    bool on;
    if (mode == 2)      on = ((const ushort_t*)raw)[e] != 0;
    else if (mode == 1) on = ((const unsigned char*)raw)[e] != 0;
    else                on = raw[e] != 0;
    maskf[e]    = on ? 1.0f : 0.0f;
    out_tail[e] = on ? 1.0f : 0.0f;
    if (!on) atomicAdd(&cnt, 1);
    __syncthreads();
    if (tid == 0) nmcnt[blockIdx.x] = cnt;
}

// ---------------------------------------------------------------------------
// Merged prep kernel: blocks [0,4096) convert weights; [4096,5120) transpose x.
// ---------------------------------------------------------------------------
__global__ __launch_bounds__(256) void prep_kernel(
    const float* __restrict__ x, const float* __restrict__ Wq,
    const float* __restrict__ Wk, const float* __restrict__ Wv,
    const float* __restrict__ Wp, ushort_t* __restrict__ XT,
    ushort_t* __restrict__ WQKV, ushort_t* __restrict__ WP) {
    __shared__ float tile[64][65];
    const int bid = blockIdx.x;
    const int tid = threadIdx.x;
    if (bid < 4096) {
        const int idx = bid * 256 + tid;  // quad index
        if (idx < 786432) {
            int row = idx >> 8;
            int qc  = idx & 255;
            const float* src = row < 1024 ? Wq : (row < 2048 ? Wk : Wv);
            float4 v = *(const float4*)&src[(size_t)(row & 1023) * CC + qc * 4];
            ushort4 pk; pk.x = f2bf(v.x); pk.y = f2bf(v.y);
            pk.z = f2bf(v.z); pk.w = f2bf(v.w);
            *(ushort4*)&WQKV[(size_t)idx * 4] = pk;
        } else {
            int j = idx - 786432;
            float4 v = *(const float4*)&Wp[(size_t)j * 4];
            ushort4 pk; pk.x = f2bf(v.x); pk.y = f2bf(v.y);
            pk.z = f2bf(v.z); pk.w = f2bf(v.w);
            *(ushort4*)&WP[(size_t)j * 4] = pk;
        }
    } else {
        const int xb = bid - 4096;
        const int t0 = (xb & 31) * 64, c0 = ((xb >> 5) & 15) * 64, b = xb >> 9;
        const int tc = tid & 15, tr = tid >> 4;
        #pragma unroll
        for (int p = 0; p < 4; p++) {
            int cl = tr + p * 16;
            float4 v = *(const float4*)&x[((size_t)b * CC + c0 + cl) * TT + t0 + tc * 4];
            tile[cl][tc * 4 + 0] = v.x; tile[cl][tc * 4 + 1] = v.y;
            tile[cl][tc * 4 + 2] = v.z; tile[cl][tc * 4 + 3] = v.w;
        }
        __syncthreads();
        #pragma unroll
        for (int p = 0; p < 4; p++) {
            int tl = tr + p * 16;
            ushort4 pk;
            pk.x = f2bf(tile[tc * 4 + 0][tl]);
            pk.y = f2bf(tile[tc * 4 + 1][tl]);
            pk.z = f2bf(tile[tc * 4 + 2][tl]);
            pk.w = f2bf(tile[tc * 4 + 3][tl]);
            *(ushort4*)&XT[((size_t)b * TT + t0 + tl) * CC + c0 + tc * 4] = pk;
        }
    }
}

// ---------------------------------------------------------------------------
// Fused QKV GEMM. q pre-scaled by QSC; K,V masked columns zeroed.
// Epilogue: packtrunc pairs (Q/K) and single-inst truncation (V) — trunc is
// magnitude-safe on softmax-normalized paths; saves ~220 VALU/thread vs RNE.
// ---------------------------------------------------------------------------
__global__ __launch_bounds__(256) void gemm_qkv_kernel(
    const ushort_t* __restrict__ Wqkv, const float* __restrict__ bq,
    const float* __restrict__ bk, const float* __restrict__ bv,
    const ushort_t* __restrict__ XT, const float* __restrict__ maskf,
    ushort_t* __restrict__ Qo, ushort_t* __restrict__ Ko,
    ushort_t* __restrict__ Vo) {
    __shared__ ushort_t As[128][32];
    __shared__ ushort_t Bs[128][32];
    __shared__ float biasS[128];

    const int b = blockIdx.z;
    const int m0 = blockIdx.y * 128;
    const int n0 = blockIdx.x * 128;
    const int tid = threadIdx.x;
    const int lane = tid & 63;
    const int w = tid >> 6;
    const int wm = (w & 1) * 64, wn = (w >> 1) * 64;
    const int la = lane & 15, lg = lane >> 4;
    const int region = m0 >> 10;  // 0=q 1=k 2=v

    const float* bsrc = region == 0 ? (bq + m0)
                      : (region == 1 ? (bk + m0 - 1024) : (bv + m0 - 2048));
    if (tid < 128) biasS[tid] = bsrc[tid];

    // per-column scale, loaded up-front: Q -> QSC; K,V -> mask
    float csc[4];
    #pragma unroll
    for (int nt = 0; nt < 4; nt++) {
        const int t = n0 + wn + nt * 16 + la;
        csc[nt] = (region == 0) ? QSC : maskf[b * TT + t];
    }

    floatx4 zero4 = {0.f, 0.f, 0.f, 0.f};
    floatx4 acc[4][4];
    #pragma unroll
    for (int mt = 0; mt < 4; mt++)
        #pragma unroll
        for (int nt = 0; nt < 4; nt++) acc[mt][nt] = zero4;

    const ushort_t* Abase = Wqkv + (size_t)m0 * CC;
    const ushort_t* Bbase = XT + ((size_t)b * TT + n0) * CC;
    const int rl = lane >> 2;
    const int cl = (lane & 3) * 8;

    for (int k0 = 0; k0 < CC; k0 += 32) {
        #pragma unroll
        for (int c = 0; c < 2; c++) {
            int row = w * 32 + c * 16;
            load_lds16(Abase + (size_t)(row + rl) * CC + k0 + cl, &As[row][0]);
            load_lds16(Bbase + (size_t)(row + rl) * CC + k0 + cl, &Bs[row][0]);
        }
        __syncthreads();
        short8 af[4], bf[4];
        #pragma unroll
        for (int mt = 0; mt < 4; mt++)
            af[mt] = *(const short8*)&As[wm + mt * 16 + la][lg * 8];
        #pragma unroll
        for (int nt = 0; nt < 4; nt++)
            bf[nt] = *(const short8*)&Bs[wn + nt * 16 + la][lg * 8];
        #pragma unroll
        for (int mt = 0; mt < 4; mt++)
            #pragma unroll
            for (int nt = 0; nt < 4; nt++)
                acc[mt][nt] = MFMA(af[mt], bf[nt], acc[mt][nt]);
        __syncthreads();
    }

    #pragma unroll
    for (int mt = 0; mt < 4; mt++) {
        const int lm = wm + mt * 16 + lg * 4;
        const int gm = m0 + lm;
        #pragma unroll
        for (int nt = 0; nt < 4; nt++) {
            const int t = n0 + wn + nt * 16 + la;
            const float sc = csc[nt];
            float v0 = (acc[mt][nt][0] + biasS[lm + 0]) * sc;
            float v1 = (acc[mt][nt][1] + biasS[lm + 1]) * sc;
            float v2 = (acc[mt][nt][2] + biasS[lm + 2]) * sc;
            float v3 = (acc[mt][nt][3] + biasS[lm + 3]) * sc;
            if (region < 2) {
                int mq = gm & 1023;
                int hh = mq >> 6, db = mq & 63;
                ushort_t* dst = (region == 0 ? Qo : Ko)
                              + (((size_t)b * HH + hh) * TT + t) * DD + db;
                uint2 pk;
                pk.x = packtrunc(v0, v1);
                pk.y = packtrunc(v2, v3);
                *(uint2*)dst = pk;
            } else {
                int c = gm & 1023;
                Vo[((size_t)b * CC + c + 0) * TT + t] = f2bf_t(v0);
                Vo[((size_t)b * CC + c + 1) * TT + t] = f2bf_t(v1);
                Vo[((size_t)b * CC + c + 2) * TT + t] = f2bf_t(v2);
                Vo[((size_t)b * CC + c + 3) * TT + t] = f2bf_t(v3);
            }
        }
    }
}

// ---------------------------------------------------------------------------
// Flash attention v7 (proven R10): split-K=2, 32x32x16 MFMA, Q in regs,
// bias-free inner loop, Schraudolph exp2. Masked keys contribute exactly
// bits(SCHRAU_I0) to l; corrected via nmcnt sums.
// ---------------------------------------------------------------------------
__global__ __launch_bounds__(256) void attn_kernel(
    const ushort_t* __restrict__ Qg, const ushort_t* __restrict__ Kg,
    const ushort_t* __restrict__ Vg, const int* __restrict__ nmcnt,
    ushort_t* __restrict__ Opart, float* __restrict__ lbuf) {
    __shared__ ushort_t Ks[2][64][72];   // [buf][key][d]
    __shared__ ushort_t Vs[2][64][72];   // [buf][d][key]

    const int sp = blockIdx.z & 1, b = blockIdx.z >> 1;
    const int hh = blockIdx.y, t0 = blockIdx.x * 128;
    const int j0base = sp * (TT / 2);
    const int tid  = threadIdx.x;
    const int lane = tid & 63;
    const int w    = tid >> 6;
    const int ln31 = lane & 31;
    const int h    = lane >> 5;
    const size_t qkbase = ((size_t)b * HH + hh) * TT * DD;
    const size_t vbase  = ((size_t)b * CC + hh * DD) * TT;

    const int tq = t0 + w * 32 + ln31;
    short8 qreg[4];
    {
        const ushort_t* qp = Qg + qkbase + (size_t)tq * DD + h * 8;
        #pragma unroll
        for (int kc = 0; kc < 4; kc++)
            qreg[kc] = *(const short8*)(qp + kc * 16);
    }

    const int srow = tid >> 2;
    const int scol = (tid & 3) * 16;

    int4 kpre0, kpre1, vpre0, vpre1;
    {
        const ushort_t* kp = Kg + qkbase + (size_t)(j0base + srow) * DD + scol;
        const ushort_t* vp = Vg + vbase + (size_t)srow * TT + j0base + scol;
        kpre0 = *(const int4*)(kp);  kpre1 = *(const int4*)(kp + 8);
        vpre0 = *(const int4*)(vp);  vpre1 = *(const int4*)(vp + 8);
    }

    float lsum = 0.0f;
    floatx16 zero16 = {0.f,0.f,0.f,0.f,0.f,0.f,0.f,0.f,
                       0.f,0.f,0.f,0.f,0.f,0.f,0.f,0.f};
    floatx16 oacc[2];
    oacc[0] = zero16; oacc[1] = zero16;

    for (int kt = 0; kt < 16; kt++) {
        const int p = kt & 1;
        *(int4*)&Ks[p][srow][scol]     = kpre0;
        *(int4*)&Ks[p][srow][scol + 8] = kpre1;
        *(int4*)&Vs[p][srow][scol]     = vpre0;
        *(int4*)&Vs[p][srow][scol + 8] = vpre1;
        if (kt < 15) {
            const int j0n = j0base + (kt + 1) * 64;
            const ushort_t* kp = Kg + qkbase + (size_t)(j0n + srow) * DD + scol;
            const ushort_t* vp = Vg + vbase + (size_t)srow * TT + j0n + scol;
            kpre0 = *(const int4*)(kp);  kpre1 = *(const int4*)(kp + 8);
            vpre0 = *(const int4*)(vp);  vpre1 = *(const int4*)(vp + 8);
        }
        __syncthreads();

        // ---- S^T = K · Q^T ----
        floatx16 sacc[2];
        sacc[0] = zero16; sacc[1] = zero16;
        #pragma unroll
        for (int kc = 0; kc < 4; kc++) {
            #pragma unroll
            for (int mt = 0; mt < 2; mt++) {
                short8 kf = *(const short8*)&Ks[p][mt * 32 + ln31][kc * 16 + h * 8];
                sacc[mt] = MFMA32(kf, qreg[kc], sacc[mt]);
            }
        }

        // ---- Schraudolph exp2 softmax: p = approx2^s ----
        float psum = 0.0f;
        unsigned int pd[16];
        #pragma unroll
        for (int mt = 0; mt < 2; mt++)
            #pragma unroll
            for (int g = 0; g < 4; g++) {
                float p0 = exp2_approx(sacc[mt][g * 4 + 0]);
                float p1 = exp2_approx(sacc[mt][g * 4 + 1]);
                float p2 = exp2_approx(sacc[mt][g * 4 + 2]);
                float p3 = exp2_approx(sacc[mt][g * 4 + 3]);
                psum += (p0 + p1) + (p2 + p3);
                pd[mt * 8 + g * 2 + 0] = packtrunc(p0, p1);
                pd[mt * 8 + g * 2 + 1] = packtrunc(p2, p3);
            }
        lsum += psum;

        // ---- PV: B-frag via half-wave exchange ----
        #pragma unroll
        for (int kc = 0; kc < 4; kc++) {
            const int base = (kc >> 1) * 8 + (kc & 1) * 4;
            int a0 = pd[base], a1 = pd[base + 1], a2 = pd[base + 2], a3 = pd[base + 3];
            int x0 = __shfl_xor(h ? a0 : a2, 32, 64);
            int x1 = __shfl_xor(h ? a1 : a3, 32, 64);
            int4 fi;
            fi.x = h ? x0 : a0;
            fi.y = h ? x1 : a1;
            fi.z = h ? a2 : x0;
            fi.w = h ? a3 : x1;
            short8 pf = *(short8*)&fi;
            #pragma unroll
            for (int dt = 0; dt < 2; dt++) {
                short8 vf = *(const short8*)&Vs[p][dt * 32 + ln31][kc * 16 + h * 8];
                oacc[dt] = MFMA32(vf, pf, oacc[dt]);
            }
        }
    }

    // full split sum; remove masked keys' exact approx(0) contributions
    lsum += __shfl_xor(lsum, 32, 64);
    {
        const int r4 = (b * 2 + sp) * 4;
        int nm = nmcnt[r4] + nmcnt[r4 + 1] + nmcnt[r4 + 2] + nmcnt[r4 + 3];
        lsum -= (float)nm * __int_as_float(SCHRAU_I0);
    }

    // ---- epilogue: Opart = O_s/l_s (bf16 RNE — O-path stays unbiased) ----
    const float inv = lsum > 0.0f ? 1.0f / lsum : 0.0f;
    ushort_t* OP = Opart + (size_t)sp * ((size_t)BB * TT * CC)
                 + ((size_t)b * TT + tq) * CC + hh * 64;
    #pragma unroll
    for (int mt = 0; mt < 2; mt++)
        #pragma unroll
        for (int g = 0; g < 4; g++) {
            int db = mt * 32 + g * 8 + h * 4;
            ushort4 pk;
            pk.x = f2bf(oacc[mt][g * 4 + 0] * inv);
            pk.y = f2bf(oacc[mt][g * 4 + 1] * inv);
            pk.z = f2bf(oacc[mt][g * 4 + 2] * inv);
            pk.w = f2bf(oacc[mt][g * 4 + 3] * inv);
            *(ushort4*)&OP[db] = pk;
        }
    if (h == 0)
        lbuf[(((size_t)sp * BB + b) * HH + hh) * TT + tq] = lsum;
}

// ---------------------------------------------------------------------------
// Combine splits: OT = w0*P0 + w1*P1, w_s = l_s/(l0+l1).
// ---------------------------------------------------------------------------
__global__ __launch_bounds__(256) void combine_kernel(
    const ushort_t* __restrict__ Opart, const float* __restrict__ lbuf,
    ushort_t* __restrict__ OT) {
    const size_t idx = ((size_t)blockIdx.x * 256 + threadIdx.x) * 8;
    const int c0 = (int)(idx & (CC - 1));
    const int t  = (int)((idx >> 10) & (TT - 1));
    const int b  = (int)(idx >> 21);
    const int hh = c0 >> 6;
    const float l0 = lbuf[(((size_t)0 * BB + b) * HH + hh) * TT + t];
    const float l1 = lbuf[(((size_t)1 * BB + b) * HH + hh) * TT + t];
    const float sum = l0 + l1;
    const float ws = sum > 0.0f ? 1.0f / sum : 0.0f;
    const float w0 = l0 * ws, w1 = l1 * ws;
    const ushort_t* P0 = Opart + idx;
    const ushort_t* P1 = Opart + (size_t)BB * TT * CC + idx;
    ushort4 a0 = *(const ushort4*)(P0);
    ushort4 a1 = *(const ushort4*)(P0 + 4);
    ushort4 b0 = *(const ushort4*)(P1);
    ushort4 b1 = *(const ushort4*)(P1 + 4);
    ushort4 o0, o1;
    o0.x = f2bf(w0 * bf2f(a0.x) + w1 * bf2f(b0.x));
    o0.y = f2bf(w0 * bf2f(a0.y) + w1 * bf2f(b0.y));
    o0.z = f2bf(w0 * bf2f(a0.z) + w1 * bf2f(b0.z));
    o0.w = f2bf(w0 * bf2f(a0.w) + w1 * bf2f(b0.w));
    o1.x = f2bf(w0 * bf2f(a1.x) + w1 * bf2f(b1.x));
    o1.y = f2bf(w0 * bf2f(a1.y) + w1 * bf2f(b1.y));
    o1.z = f2bf(w0 * bf2f(a1.z) + w1 * bf2f(b1.z));
    o1.w = f2bf(w0 * bf2f(a1.w) + w1 * bf2f(b1.w));
    *(ushort4*)&OT[idx]     = o0;
    *(ushort4*)&OT[idx + 4] = o1;
}

// ---------------------------------------------------------------------------
// Output GEMM, single-pass bf16 (proven R7/R8).
// ---------------------------------------------------------------------------
__global__ __launch_bounds__(256) void gemm_out_kernel(
    const ushort_t* __restrict__ WP, const ushort_t* __restrict__ OT,
    const float* __restrict__ bp, const float* __restrict__ maskf,
    float* __restrict__ out) {
    __shared__ ushort_t As[64][32];
    __shared__ ushort_t Bs[128][32];
    __shared__ float biasS[64];

    const int b = blockIdx.z;
    const int m0 = blockIdx.y * 64;
    const int n0 = blockIdx.x * 128;
    const int tid = threadIdx.x;
    const int lane = tid & 63;
    const int w = tid >> 6;
    const int wm = (w & 1) * 32, wn = (w >> 1) * 64;
    const int la = lane & 15, lg = lane >> 4;

    if (tid < 64) biasS[tid] = bp[m0 + tid];

    floatx4 zero4 = {0.f, 0.f, 0.f, 0.f};
    floatx4 acc[2][4];
    #pragma unroll
    for (int mt = 0; mt < 2; mt++)
        #pragma unroll
        for (int nt = 0; nt < 4; nt++) acc[mt][nt] = zero4;

    const int rl = lane >> 2;
    const int cl = (lane & 3) * 8;
    const ushort_t* Bbase = OT + ((size_t)b * TT + n0) * CC;

    for (int k0 = 0; k0 < CC; k0 += 32) {
        {
            int row = w * 16;
            load_lds16(WP + (size_t)(m0 + row + rl) * CC + k0 + cl, &As[row][0]);
        }
        #pragma unroll
        for (int c = 0; c < 2; c++) {
            int row = w * 32 + c * 16;
            load_lds16(Bbase + (size_t)(row + rl) * CC + k0 + cl, &Bs[row][0]);
        }
        __syncthreads();
        short8 af[2], bf[4];
        #pragma unroll
        for (int mt = 0; mt < 2; mt++)
            af[mt] = *(const short8*)&As[wm + mt * 16 + la][lg * 8];
        #pragma unroll
        for (int nt = 0; nt < 4; nt++)
            bf[nt] = *(const short8*)&Bs[wn + nt * 16 + la][lg * 8];
        #pragma unroll
        for (int mt = 0; mt < 2; mt++)
            #pragma unroll
            for (int nt = 0; nt < 4; nt++)
                acc[mt][nt] = MFMA(af[mt], bf[nt], acc[mt][nt]);
        __syncthreads();
    }

    #pragma unroll
    for (int mt = 0; mt < 2; mt++) {
        const int lm = wm + mt * 16 + lg * 4;
        #pragma unroll
        for (int nt = 0; nt < 4; nt++) {
            const int t = n0 + wn + nt * 16 + la;
            const float mk = maskf[b * TT + t];
            #pragma unroll
            for (int r = 0; r < 4; r++)
                out[((size_t)b * CC + m0 + lm + r) * TT + t] =
                    (acc[mt][nt][r] + biasS[lm + r]) * mk;
        }
    }
}

// ---------------------------------------------------------------------------
extern "C" void kernel_launch(void* const* d_in, const int* in_sizes, int n_in,
                              void* d_out, int out_size, void* d_ws,
                              size_t ws_size, hipStream_t stream) {
    const float* x    = (const float*)d_in[0];
    const void*  mask = d_in[1];
    const float* Wq   = (const float*)d_in[2];
    const float* bq   = (const float*)d_in[3];
    const float* Wk   = (const float*)d_in[4];
    const float* bk   = (const float*)d_in[5];
    const float* Wv   = (const float*)d_in[6];
    const float* bv   = (const float*)d_in[7];
    const float* Wp   = (const float*)d_in[8];
    const float* bp   = (const float*)d_in[9];

    float* out  = (float*)d_out;
    float* wsf  = (float*)d_ws;
    int* nmcnt  = (int*)d_ws + 16;     // 16 per-block masked counts
    float* maskf = wsf + 1024;
    char* wsb = (char*)d_ws;
    ushort_t* XT    = (ushort_t*)(wsb + XT_OFF);   // also final OT
    ushort_t* WQKV  = (ushort_t*)(wsb + WQKV_OFF);
    ushort_t* WPb   = (ushort_t*)(wsb + WP_OFF);
    ushort_t* Qb    = (ushort_t*)(wsb + Q_OFF);
    ushort_t* Kb    = (ushort_t*)(wsb + K_OFF);
    ushort_t* Vb    = (ushort_t*)(wsb + V_OFF);
    ushort_t* Opart = (ushort_t*)(wsb + OP_OFF);
    float*    lbuf  = (float*)(wsb + ML_OFF);

    mask_kernel<<<16, 256, 0, stream>>>((const unsigned int*)mask, maskf,
                                        nmcnt, out + (size_t)BB * CC * TT);
    prep_kernel<<<5120, 256, 0, stream>>>(x, Wq, Wk, Wv, Wp, XT, WQKV, WPb);

    gemm_qkv_kernel<<<dim3(TT / 128, 3 * CC / 128, BB), 256, 0, stream>>>(
        WQKV, bq, bk, bv, XT, maskf, Qb, Kb, Vb);

    attn_kernel<<<dim3(TT / 128, HH, BB * 2), 256, 0, stream>>>(
        Qb, Kb, Vb, nmcnt, Opart, lbuf);

    combine_kernel<<<2048, 256, 0, stream>>>(Opart, lbuf, XT);

    gemm_out_kernel<<<dim3(TT / 128, CC / 64, BB), 256, 0, stream>>>(
        WPb, XT, bp, maskf, out);
}

// Round 12
// 207.052 us; speedup vs baseline: 1.1628x; 1.0050x over previous
//
#include <hip/hip_runtime.h>
#include <hip/hip_bf16.h>
#include <math.h>

#define BB 2
#define CC 1024
#define TT 2048
#define HH 16
#define DD 64

using short8   = __attribute__((ext_vector_type(8))) short;
using floatx4  = __attribute__((ext_vector_type(4))) float;
using floatx16 = __attribute__((ext_vector_type(16))) float;
typedef unsigned short ushort_t;

#define MFMA(a, b, c) __builtin_amdgcn_mfma_f32_16x16x32_bf16((a), (b), (c), 0, 0, 0)
#define MFMA32(a, b, c) __builtin_amdgcn_mfma_f32_32x32x16_bf16((a), (b), (c), 0, 0, 0)

// Q pre-scale: SCALE * log2(e) so attn softmax runs in exp2 domain.
#define QSC 0.18033688011112042f

// Schraudolph fast exp2 (2 full-rate VALU ops). approx(0) = bits(SCHRAU_I0).
#define SCHRAU_B 1064866816.0f
#define SCHRAU_I0 1064866816
__device__ __forceinline__ float exp2_approx(float x) {
    int i = (int)(fmaf(x, 8388608.0f, SCHRAU_B));
    return __int_as_float(i);
}

__device__ __forceinline__ ushort_t f2bf(float f) {          // RNE (O-path)
    unsigned int u = __float_as_uint(f);
    u += 0x7FFFu + ((u >> 16) & 1u);
    return (ushort_t)(u >> 16);
}
__device__ __forceinline__ float bf2f(ushort_t h) {
    return __uint_as_float(((unsigned int)h) << 16);
}
__device__ __forceinline__ ushort_t f2bf_t(float f) {        // truncation
    return (ushort_t)(__float_as_uint(f) >> 16);
}
// single v_perm_b32: pack high halves of two floats (truncation to bf16)
__device__ __forceinline__ unsigned int packtrunc(float a, float b) {
    return __builtin_amdgcn_perm(__float_as_uint(b), __float_as_uint(a),
                                 0x07060302u);
}
// async global->LDS, 16B per lane, dest = uniform base + lane*16
__device__ __forceinline__ void load_lds16(const void* g, void* s) {
    __builtin_amdgcn_global_load_lds(
        (const __attribute__((address_space(1))) void*)g,
        (__attribute__((address_space(3))) void*)s, 16, 0, 0);
}

// ---- workspace byte offsets (bf16 arena starts at 64KB) --------------------
static constexpr size_t B0       = 65536;
static constexpr size_t XT_OFF   = B0;                       // [B][T][C] bf16; later reused for OT
static constexpr size_t WQKV_OFF = XT_OFF   + 8388608;       // [3072][1024]
static constexpr size_t WP_OFF   = WQKV_OFF + 6291456;       // [1024][1024]
static constexpr size_t Q_OFF    = WP_OFF   + 2097152;       // [B][H][T][D]
static constexpr size_t K_OFF    = Q_OFF    + 8388608;
static constexpr size_t V_OFF    = K_OFF    + 8388608;       // [B][C][T]
static constexpr size_t OP_OFF   = V_OFF    + 8388608;       // Opart[2][B][T][C] bf16
static constexpr size_t ML_OFF   = OP_OFF   + 16777216;      // l[2][B][H][T] fp32

// ---------------------------------------------------------------------------
// Merged prep kernel:
//   blocks [0,4096)      : weight conversion (WQKV, WP)
//   blocks [4096,5120)   : x transpose -> XT bf16
//   blocks [5120,5136)   : mask expand (self-detecting dtype) + nmcnt
// ---------------------------------------------------------------------------
__global__ __launch_bounds__(256) void prep_kernel(
    const float* __restrict__ x, const float* __restrict__ Wq,
    const float* __restrict__ Wk, const float* __restrict__ Wv,
    const float* __restrict__ Wp, const unsigned int* __restrict__ mraw,
    ushort_t* __restrict__ XT, ushort_t* __restrict__ WQKV,
    ushort_t* __restrict__ WP, float* __restrict__ maskf,
    int* __restrict__ nmcnt, float* __restrict__ out_tail) {
    __shared__ float tile[64][65];
    const int bid = blockIdx.x;
    const int tid = threadIdx.x;
    if (bid < 4096) {
        const int idx = bid * 256 + tid;  // quad index
        if (idx < 786432) {
            int row = idx >> 8;
            int qc  = idx & 255;
            const float* src = row < 1024 ? Wq : (row < 2048 ? Wk : Wv);
            float4 v = *(const float4*)&src[(size_t)(row & 1023) * CC + qc * 4];
            ushort4 pk; pk.x = f2bf(v.x); pk.y = f2bf(v.y);
            pk.z = f2bf(v.z); pk.w = f2bf(v.w);
            *(ushort4*)&WQKV[(size_t)idx * 4] = pk;
        } else {
            int j = idx - 786432;
            float4 v = *(const float4*)&Wp[(size_t)j * 4];
            ushort4 pk; pk.x = f2bf(v.x); pk.y = f2bf(v.y);
            pk.z = f2bf(v.z); pk.w = f2bf(v.w);
            *(ushort4*)&WP[(size_t)j * 4] = pk;
        }
    } else if (bid < 5120) {
        const int xb = bid - 4096;
        const int t0 = (xb & 31) * 64, c0 = ((xb >> 5) & 15) * 64, b = xb >> 9;
        const int tc = tid & 15, tr = tid >> 4;
        #pragma unroll
        for (int p = 0; p < 4; p++) {
            int cl = tr + p * 16;
            float4 v = *(const float4*)&x[((size_t)b * CC + c0 + cl) * TT + t0 + tc * 4];
            tile[cl][tc * 4 + 0] = v.x; tile[cl][tc * 4 + 1] = v.y;
            tile[cl][tc * 4 + 2] = v.z; tile[cl][tc * 4 + 3] = v.w;
        }
        __syncthreads();
        #pragma unroll
        for (int p = 0; p < 4; p++) {
            int tl = tr + p * 16;
            ushort4 pk;
            pk.x = f2bf(tile[tc * 4 + 0][tl]);
            pk.y = f2bf(tile[tc * 4 + 1][tl]);
            pk.z = f2bf(tile[tc * 4 + 2][tl]);
            pk.w = f2bf(tile[tc * 4 + 3][tl]);
            *(ushort4*)&XT[((size_t)b * TT + t0 + tl) * CC + c0 + tc * 4] = pk;
        }
    } else {
        __shared__ int ev_bf16, ev_bool, cnt;
        const int mb = bid - 5120;      // 0..15
        if (tid == 0) { ev_bf16 = 0; ev_bool = 0; cnt = 0; }
        __syncthreads();
        for (int i = tid; i < 1024; i += 256) {
            unsigned int w = mraw[i];
            if ((w & 0xFFFFu) == 0x3F80u) atomicOr(&ev_bf16, 1);
            if ((w & 0xFFFFFF00u) != 0u && w != 0x3F800000u) atomicOr(&ev_bool, 1);
        }
        __syncthreads();
        const int mode = ev_bf16 ? 2 : (ev_bool ? 1 : 0);
        const int e = mb * 256 + tid;
        bool on;
        if (mode == 2)      on = ((const ushort_t*)mraw)[e] != 0;
        else if (mode == 1) on = ((const unsigned char*)mraw)[e] != 0;
        else                on = mraw[e] != 0;
        maskf[e]    = on ? 1.0f : 0.0f;
        out_tail[e] = on ? 1.0f : 0.0f;
        if (!on) atomicAdd(&cnt, 1);
        __syncthreads();
        if (tid == 0) nmcnt[mb] = cnt;
    }
}

// ---------------------------------------------------------------------------
// Fused QKV GEMM (proven R11). q pre-scaled by QSC; K,V masked columns zeroed.
// ---------------------------------------------------------------------------
__global__ __launch_bounds__(256) void gemm_qkv_kernel(
    const ushort_t* __restrict__ Wqkv, const float* __restrict__ bq,
    const float* __restrict__ bk, const float* __restrict__ bv,
    const ushort_t* __restrict__ XT, const float* __restrict__ maskf,
    ushort_t* __restrict__ Qo, ushort_t* __restrict__ Ko,
    ushort_t* __restrict__ Vo) {
    __shared__ ushort_t As[128][32];
    __shared__ ushort_t Bs[128][32];
    __shared__ float biasS[128];

    const int b = blockIdx.z;
    const int m0 = blockIdx.y * 128;
    const int n0 = blockIdx.x * 128;
    const int tid = threadIdx.x;
    const int lane = tid & 63;
    const int w = tid >> 6;
    const int wm = (w & 1) * 64, wn = (w >> 1) * 64;
    const int la = lane & 15, lg = lane >> 4;
    const int region = m0 >> 10;  // 0=q 1=k 2=v

    const float* bsrc = region == 0 ? (bq + m0)
                      : (region == 1 ? (bk + m0 - 1024) : (bv + m0 - 2048));
    if (tid < 128) biasS[tid] = bsrc[tid];

    // per-column scale, loaded up-front: Q -> QSC; K,V -> mask
    float csc[4];
    #pragma unroll
    for (int nt = 0; nt < 4; nt++) {
        const int t = n0 + wn + nt * 16 + la;
        csc[nt] = (region == 0) ? QSC : maskf[b * TT + t];
    }

    floatx4 zero4 = {0.f, 0.f, 0.f, 0.f};
    floatx4 acc[4][4];
    #pragma unroll
    for (int mt = 0; mt < 4; mt++)
        #pragma unroll
        for (int nt = 0; nt < 4; nt++) acc[mt][nt] = zero4;

    const ushort_t* Abase = Wqkv + (size_t)m0 * CC;
    const ushort_t* Bbase = XT + ((size_t)b * TT + n0) * CC;
    const int rl = lane >> 2;
    const int cl = (lane & 3) * 8;

    for (int k0 = 0; k0 < CC; k0 += 32) {
        #pragma unroll
        for (int c = 0; c < 2; c++) {
            int row = w * 32 + c * 16;
            load_lds16(Abase + (size_t)(row + rl) * CC + k0 + cl, &As[row][0]);
            load_lds16(Bbase + (size_t)(row + rl) * CC + k0 + cl, &Bs[row][0]);
        }
        __syncthreads();
        short8 af[4], bf[4];
        #pragma unroll
        for (int mt = 0; mt < 4; mt++)
            af[mt] = *(const short8*)&As[wm + mt * 16 + la][lg * 8];
        #pragma unroll
        for (int nt = 0; nt < 4; nt++)
            bf[nt] = *(const short8*)&Bs[wn + nt * 16 + la][lg * 8];
        #pragma unroll
        for (int mt = 0; mt < 4; mt++)
            #pragma unroll
            for (int nt = 0; nt < 4; nt++)
                acc[mt][nt] = MFMA(af[mt], bf[nt], acc[mt][nt]);
        __syncthreads();
    }

    #pragma unroll
    for (int mt = 0; mt < 4; mt++) {
        const int lm = wm + mt * 16 + lg * 4;
        const int gm = m0 + lm;
        #pragma unroll
        for (int nt = 0; nt < 4; nt++) {
            const int t = n0 + wn + nt * 16 + la;
            const float sc = csc[nt];
            float v0 = (acc[mt][nt][0] + biasS[lm + 0]) * sc;
            float v1 = (acc[mt][nt][1] + biasS[lm + 1]) * sc;
            float v2 = (acc[mt][nt][2] + biasS[lm + 2]) * sc;
            float v3 = (acc[mt][nt][3] + biasS[lm + 3]) * sc;
            if (region < 2) {
                int mq = gm & 1023;
                int hh = mq >> 6, db = mq & 63;
                ushort_t* dst = (region == 0 ? Qo : Ko)
                              + (((size_t)b * HH + hh) * TT + t) * DD + db;
                uint2 pk;
                pk.x = packtrunc(v0, v1);
                pk.y = packtrunc(v2, v3);
                *(uint2*)dst = pk;
            } else {
                int c = gm & 1023;
                Vo[((size_t)b * CC + c + 0) * TT + t] = f2bf_t(v0);
                Vo[((size_t)b * CC + c + 1) * TT + t] = f2bf_t(v1);
                Vo[((size_t)b * CC + c + 2) * TT + t] = f2bf_t(v2);
                Vo[((size_t)b * CC + c + 3) * TT + t] = f2bf_t(v3);
            }
        }
    }
}

// ---------------------------------------------------------------------------
// Flash attention v8: TRUE software pipeline — K/V loads for tile kt+1 are
// issued AFTER the barrier (in flight across tile kt's compute), not before
// it (where __syncthreads' vmcnt(0) drain would serialize them — the R11
// structure exposed full global-load latency every tile: 30% idle).
// ---------------------------------------------------------------------------
__global__ __launch_bounds__(256) void attn_kernel(
    const ushort_t* __restrict__ Qg, const ushort_t* __restrict__ Kg,
    const ushort_t* __restrict__ Vg, const int* __restrict__ nmcnt,
    ushort_t* __restrict__ Opart, float* __restrict__ lbuf) {
    __shared__ ushort_t Ks[2][64][72];   // [buf][key][d]
    __shared__ ushort_t Vs[2][64][72];   // [buf][d][key]

    const int sp = blockIdx.z & 1, b = blockIdx.z >> 1;
    const int hh = blockIdx.y, t0 = blockIdx.x * 128;
    const int j0base = sp * (TT / 2);
    const int tid  = threadIdx.x;
    const int lane = tid & 63;
    const int w    = tid >> 6;
    const int ln31 = lane & 31;
    const int h    = lane >> 5;
    const size_t qkbase = ((size_t)b * HH + hh) * TT * DD;
    const size_t vbase  = ((size_t)b * CC + hh * DD) * TT;

    const int tq = t0 + w * 32 + ln31;
    short8 qreg[4];
    {
        const ushort_t* qp = Qg + qkbase + (size_t)tq * DD + h * 8;
        #pragma unroll
        for (int kc = 0; kc < 4; kc++)
            qreg[kc] = *(const short8*)(qp + kc * 16);
    }

    const int srow = tid >> 2;
    const int scol = (tid & 3) * 16;
    const ushort_t* kbase = Kg + qkbase + (size_t)srow * DD + scol;
    const ushort_t* vbptr = Vg + vbase + (size_t)srow * TT + scol;

    // prologue: issue loads for tile 0
    int4 kpre0, kpre1, vpre0, vpre1;
    {
        const ushort_t* kp = kbase + (size_t)j0base * DD;
        const ushort_t* vp = vbptr + j0base;
        kpre0 = *(const int4*)(kp);  kpre1 = *(const int4*)(kp + 8);
        vpre0 = *(const int4*)(vp);  vpre1 = *(const int4*)(vp + 8);
    }

    float lsum = 0.0f;
    floatx16 zero16 = {0.f,0.f,0.f,0.f,0.f,0.f,0.f,0.f,
                       0.f,0.f,0.f,0.f,0.f,0.f,0.f,0.f};
    floatx16 oacc[2];
    oacc[0] = zero16; oacc[1] = zero16;

    for (int kt = 0; kt < 16; kt++) {
        const int p = kt & 1;
        // store tile kt (waits on its loads — which had a full tile to land)
        *(int4*)&Ks[p][srow][scol]     = kpre0;
        *(int4*)&Ks[p][srow][scol + 8] = kpre1;
        *(int4*)&Vs[p][srow][scol]     = vpre0;
        *(int4*)&Vs[p][srow][scol + 8] = vpre1;
        __syncthreads();
        // issue loads for tile kt+1 AFTER the barrier: in flight during compute
        if (kt < 15) {
            const int j0n = j0base + (kt + 1) * 64;
            const ushort_t* kp = kbase + (size_t)j0n * DD;
            const ushort_t* vp = vbptr + j0n;
            kpre0 = *(const int4*)(kp);  kpre1 = *(const int4*)(kp + 8);
            vpre0 = *(const int4*)(vp);  vpre1 = *(const int4*)(vp + 8);
        }

        // ---- S^T = K · Q^T ----
        floatx16 sacc[2];
        sacc[0] = zero16; sacc[1] = zero16;
        #pragma unroll
        for (int kc = 0; kc < 4; kc++) {
            #pragma unroll
            for (int mt = 0; mt < 2; mt++) {
                short8 kf = *(const short8*)&Ks[p][mt * 32 + ln31][kc * 16 + h * 8];
                sacc[mt] = MFMA32(kf, qreg[kc], sacc[mt]);
            }
        }

        // ---- Schraudolph exp2 softmax: p = approx2^s ----
        float psum = 0.0f;
        unsigned int pd[16];
        #pragma unroll
        for (int mt = 0; mt < 2; mt++)
            #pragma unroll
            for (int g = 0; g < 4; g++) {
                float p0 = exp2_approx(sacc[mt][g * 4 + 0]);
                float p1 = exp2_approx(sacc[mt][g * 4 + 1]);
                float p2 = exp2_approx(sacc[mt][g * 4 + 2]);
                float p3 = exp2_approx(sacc[mt][g * 4 + 3]);
                psum += (p0 + p1) + (p2 + p3);
                pd[mt * 8 + g * 2 + 0] = packtrunc(p0, p1);
                pd[mt * 8 + g * 2 + 1] = packtrunc(p2, p3);
            }
        lsum += psum;

        // ---- PV: B-frag via half-wave exchange ----
        #pragma unroll
        for (int kc = 0; kc < 4; kc++) {
            const int base = (kc >> 1) * 8 + (kc & 1) * 4;
            int a0 = pd[base], a1 = pd[base + 1], a2 = pd[base + 2], a3 = pd[base + 3];
            int x0 = __shfl_xor(h ? a0 : a2, 32, 64);
            int x1 = __shfl_xor(h ? a1 : a3, 32, 64);
            int4 fi;
            fi.x = h ? x0 : a0;
            fi.y = h ? x1 : a1;
            fi.z = h ? a2 : x0;
            fi.w = h ? a3 : x1;
            short8 pf = *(short8*)&fi;
            #pragma unroll
            for (int dt = 0; dt < 2; dt++) {
                short8 vf = *(const short8*)&Vs[p][dt * 32 + ln31][kc * 16 + h * 8];
                oacc[dt] = MFMA32(vf, pf, oacc[dt]);
            }
        }
    }

    // full split sum; remove masked keys' exact approx(0) contributions
    lsum += __shfl_xor(lsum, 32, 64);
    {
        const int r4 = (b * 2 + sp) * 4;
        int nm = nmcnt[r4] + nmcnt[r4 + 1] + nmcnt[r4 + 2] + nmcnt[r4 + 3];
        lsum -= (float)nm * __int_as_float(SCHRAU_I0);
    }

    // ---- epilogue: Opart = O_s/l_s (bf16 RNE — O-path stays unbiased) ----
    const float inv = lsum > 0.0f ? 1.0f / lsum : 0.0f;
    ushort_t* OP = Opart + (size_t)sp * ((size_t)BB * TT * CC)
                 + ((size_t)b * TT + tq) * CC + hh * 64;
    #pragma unroll
    for (int mt = 0; mt < 2; mt++)
        #pragma unroll
        for (int g = 0; g < 4; g++) {
            int db = mt * 32 + g * 8 + h * 4;
            ushort4 pk;
            pk.x = f2bf(oacc[mt][g * 4 + 0] * inv);
            pk.y = f2bf(oacc[mt][g * 4 + 1] * inv);
            pk.z = f2bf(oacc[mt][g * 4 + 2] * inv);
            pk.w = f2bf(oacc[mt][g * 4 + 3] * inv);
            *(ushort4*)&OP[db] = pk;
        }
    if (h == 0)
        lbuf[(((size_t)sp * BB + b) * HH + hh) * TT + tq] = lsum;
}

// ---------------------------------------------------------------------------
// Combine splits: OT = w0*P0 + w1*P1, w_s = l_s/(l0+l1).
// ---------------------------------------------------------------------------
__global__ __launch_bounds__(256) void combine_kernel(
    const ushort_t* __restrict__ Opart, const float* __restrict__ lbuf,
    ushort_t* __restrict__ OT) {
    const size_t idx = ((size_t)blockIdx.x * 256 + threadIdx.x) * 8;
    const int c0 = (int)(idx & (CC - 1));
    const int t  = (int)((idx >> 10) & (TT - 1));
    const int b  = (int)(idx >> 21);
    const int hh = c0 >> 6;
    const float l0 = lbuf[(((size_t)0 * BB + b) * HH + hh) * TT + t];
    const float l1 = lbuf[(((size_t)1 * BB + b) * HH + hh) * TT + t];
    const float sum = l0 + l1;
    const float ws = sum > 0.0f ? 1.0f / sum : 0.0f;
    const float w0 = l0 * ws, w1 = l1 * ws;
    const ushort_t* P0 = Opart + idx;
    const ushort_t* P1 = Opart + (size_t)BB * TT * CC + idx;
    ushort4 a0 = *(const ushort4*)(P0);
    ushort4 a1 = *(const ushort4*)(P0 + 4);
    ushort4 b0 = *(const ushort4*)(P1);
    ushort4 b1 = *(const ushort4*)(P1 + 4);
    ushort4 o0, o1;
    o0.x = f2bf(w0 * bf2f(a0.x) + w1 * bf2f(b0.x));
    o0.y = f2bf(w0 * bf2f(a0.y) + w1 * bf2f(b0.y));
    o0.z = f2bf(w0 * bf2f(a0.z) + w1 * bf2f(b0.z));
    o0.w = f2bf(w0 * bf2f(a0.w) + w1 * bf2f(b0.w));
    o1.x = f2bf(w0 * bf2f(a1.x) + w1 * bf2f(b1.x));
    o1.y = f2bf(w0 * bf2f(a1.y) + w1 * bf2f(b1.y));
    o1.z = f2bf(w0 * bf2f(a1.z) + w1 * bf2f(b1.z));
    o1.w = f2bf(w0 * bf2f(a1.w) + w1 * bf2f(b1.w));
    *(ushort4*)&OT[idx]     = o0;
    *(ushort4*)&OT[idx + 4] = o1;
}

// ---------------------------------------------------------------------------
// Output GEMM, single-pass bf16 (proven R7/R8).
// ---------------------------------------------------------------------------
__global__ __launch_bounds__(256) void gemm_out_kernel(
    const ushort_t* __restrict__ WP, const ushort_t* __restrict__ OT,
    const float* __restrict__ bp, const float* __restrict__ maskf,
    float* __restrict__ out) {
    __shared__ ushort_t As[64][32];
    __shared__ ushort_t Bs[128][32];
    __shared__ float biasS[64];

    const int b = blockIdx.z;
    const int m0 = blockIdx.y * 64;
    const int n0 = blockIdx.x * 128;
    const int tid = threadIdx.x;
    const int lane = tid & 63;
    const int w = tid >> 6;
    const int wm = (w & 1) * 32, wn = (w >> 1) * 64;
    const int la = lane & 15, lg = lane >> 4;

    if (tid < 64) biasS[tid] = bp[m0 + tid];

    floatx4 zero4 = {0.f, 0.f, 0.f, 0.f};
    floatx4 acc[2][4];
    #pragma unroll
    for (int mt = 0; mt < 2; mt++)
        #pragma unroll
        for (int nt = 0; nt < 4; nt++) acc[mt][nt] = zero4;

    const int rl = lane >> 2;
    const int cl = (lane & 3) * 8;
    const ushort_t* Bbase = OT + ((size_t)b * TT + n0) * CC;

    for (int k0 = 0; k0 < CC; k0 += 32) {
        {
            int row = w * 16;
            load_lds16(WP + (size_t)(m0 + row + rl) * CC + k0 + cl, &As[row][0]);
        }
        #pragma unroll
        for (int c = 0; c < 2; c++) {
            int row = w * 32 + c * 16;
            load_lds16(Bbase + (size_t)(row + rl) * CC + k0 + cl, &Bs[row][0]);
        }
        __syncthreads();
        short8 af[2], bf[4];
        #pragma unroll
        for (int mt = 0; mt < 2; mt++)
            af[mt] = *(const short8*)&As[wm + mt * 16 + la][lg * 8];
        #pragma unroll
        for (int nt = 0; nt < 4; nt++)
            bf[nt] = *(const short8*)&Bs[wn + nt * 16 + la][lg * 8];
        #pragma unroll
        for (int mt = 0; mt < 2; mt++)
            #pragma unroll
            for (int nt = 0; nt < 4; nt++)
                acc[mt][nt] = MFMA(af[mt], bf[nt], acc[mt][nt]);
        __syncthreads();
    }

    #pragma unroll
    for (int mt = 0; mt < 2; mt++) {
        const int lm = wm + mt * 16 + lg * 4;
        #pragma unroll
        for (int nt = 0; nt < 4; nt++) {
            const int t = n0 + wn + nt * 16 + la;
            const float mk = maskf[b * TT + t];
            #pragma unroll
            for (int r = 0; r < 4; r++)
                out[((size_t)b * CC + m0 + lm + r) * TT + t] =
                    (acc[mt][nt][r] + biasS[lm + r]) * mk;
        }
    }
}

// ---------------------------------------------------------------------------
extern "C" void kernel_launch(void* const* d_in, const int* in_sizes, int n_in,
                              void* d_out, int out_size, void* d_ws,
                              size_t ws_size, hipStream_t stream) {
    const float* x    = (const float*)d_in[0];
    const void*  mask = d_in[1];
    const float* Wq   = (const float*)d_in[2];
    const float* bq   = (const float*)d_in[3];
    const float* Wk   = (const float*)d_in[4];
    const float* bk   = (const float*)d_in[5];
    const float* Wv   = (const float*)d_in[6];
    const float* bv   = (const float*)d_in[7];
    const float* Wp   = (const float*)d_in[8];
    const float* bp   = (const float*)d_in[9];

    float* out  = (float*)d_out;
    float* wsf  = (float*)d_ws;
    int* nmcnt  = (int*)d_ws + 16;     // 16 per-block masked counts
    float* maskf = wsf + 1024;
    char* wsb = (char*)d_ws;
    ushort_t* XT    = (ushort_t*)(wsb + XT_OFF);   // also final OT
    ushort_t* WQKV  = (ushort_t*)(wsb + WQKV_OFF);
    ushort_t* WPb   = (ushort_t*)(wsb + WP_OFF);
    ushort_t* Qb    = (ushort_t*)(wsb + Q_OFF);
    ushort_t* Kb    = (ushort_t*)(wsb + K_OFF);
    ushort_t* Vb    = (ushort_t*)(wsb + V_OFF);
    ushort_t* Opart = (ushort_t*)(wsb + OP_OFF);
    float*    lbuf  = (float*)(wsb + ML_OFF);

    prep_kernel<<<5136, 256, 0, stream>>>(x, Wq, Wk, Wv, Wp,
                                          (const unsigned int*)mask, XT, WQKV,
                                          WPb, maskf, nmcnt,
                                          out + (size_t)BB * CC * TT);

    gemm_qkv_kernel<<<dim3(TT / 128, 3 * CC / 128, BB), 256, 0, stream>>>(
        WQKV, bq, bk, bv, XT, maskf, Qb, Kb, Vb);

    attn_kernel<<<dim3(TT / 128, HH, BB * 2), 256, 0, stream>>>(
        Qb, Kb, Vb, nmcnt, Opart, lbuf);

    combine_kernel<<<2048, 256, 0, stream>>>(Opart, lbuf, XT);

    gemm_out_kernel<<<dim3(TT / 128, CC / 64, BB), 256, 0, stream>>>(
        WPb, XT, bp, maskf, out);
}